// Round 6
// baseline (1089.794 us; speedup 1.0000x reference)
//
#include <hip/hip_runtime.h>
#include <hip/hip_bf16.h>

#define B_ 64
#define L_ 1024
#define D_ 256
#define M_ (B_*L_)

typedef __attribute__((ext_vector_type(8))) short s16x8;
typedef __attribute__((ext_vector_type(4))) float f32x4;

__device__ __forceinline__ float sigmoidf_(float z) { return 1.0f/(1.0f + __expf(-z)); }

__device__ __forceinline__ unsigned short f2bf(float x) {
  unsigned int u = __builtin_bit_cast(unsigned int, x);
  u += 0x7fffu + ((u >> 16) & 1u);          // RNE
  return (unsigned short)(u >> 16);
}
__device__ __forceinline__ float bf2f(unsigned short u) {
  unsigned int x = ((unsigned int)u) << 16;
  return __builtin_bit_cast(float, x);
}
__device__ __forceinline__ uint4 pack8(const float* f) {
  union { unsigned short u[8]; uint4 v; } r;
  #pragma unroll
  for (int i = 0; i < 8; ++i) r.u[i] = f2bf(f[i]);
  return r.v;
}
__device__ __forceinline__ s16x8 pack8v(const float* f) {
  union { unsigned short u[8]; s16x8 v; } r;
  #pragma unroll
  for (int i = 0; i < 8; ++i) r.u[i] = f2bf(f[i]);
  return r.v;
}

// ---------------- K1: gather+convert+transpose -----------------------------
__global__ __launch_bounds__(256) void k_embedT(const int* __restrict__ qs,
    const float* __restrict__ Eq, unsigned short* __restrict__ qe_bf,
    unsigned short* __restrict__ qeT) {
  __shared__ unsigned short tile[64*264];
  int jc = blockIdx.x;
  int b  = blockIdx.y;
  int t = threadIdx.x;
  int jr = t >> 2, seg = (t & 3) * 64;
  size_t bL = (size_t)b * L_;
  int q = qs[bL + jc*64 + jr];
  {
    const float4* src = (const float4*)(Eq + (size_t)q*D_ + seg);
    float f[8];
    #pragma unroll
    for (int m = 0; m < 8; ++m) {
      float4 v0 = src[2*m], v1 = src[2*m+1];
      f[0]=v0.x; f[1]=v0.y; f[2]=v0.z; f[3]=v0.w;
      f[4]=v1.x; f[5]=v1.y; f[6]=v1.z; f[7]=v1.w;
      *(uint4*)&tile[jr*264 + seg + m*8] = pack8(f);
    }
  }
  __syncthreads();
  {
    unsigned short* dst = qe_bf + (bL + jc*64 + jr)*D_ + seg;
    #pragma unroll
    for (int m = 0; m < 8; ++m)
      *(uint4*)(dst + m*8) = *(const uint4*)&tile[jr*264 + seg + m*8];
  }
  {
    int d = t;
    union { unsigned short u[64]; uint4 v[8]; } row;
    #pragma unroll
    for (int j = 0; j < 64; ++j) row.u[j] = tile[j*264 + d];
    unsigned short* dst = qeT + ((size_t)b*D_ + d)*L_ + jc*64;
    #pragma unroll
    for (int m = 0; m < 8; ++m) *(uint4*)(dst + m*8) = row.v[m];
  }
}

// ---------------- K2: MFMA fused causal attention (unchanged, R5-valid) ----
#define KSTR 264
#define TSTR 40
#define PSTR 40

__global__ __launch_bounds__(256) void k_attn_mfma(
    const unsigned short* __restrict__ qe_bf, const unsigned short* __restrict__ qeT,
    const int* __restrict__ cs, unsigned short* __restrict__ attq,
    float* __restrict__ stv, float* __restrict__ s1v) {
  __shared__ unsigned short sK[32*KSTR];
  __shared__ unsigned short sKT[256*TSTR];
  __shared__ unsigned short sP[64*PSTR];
  __shared__ float scj[32];
  __shared__ float redz[64], reds1[64], redzd[64];
  const int ord16[16] = {15,14,13,12, 8,9,10,11, 7,6,5,4, 0,1,2,3};
  int pos = blockIdx.x >> 6, b = blockIdx.x & 63;
  int t64 = ord16[pos];
  int i0 = t64 * 64;
  int t = threadIdx.x;
  int lane = t & 63, wv = t >> 6;
  int l15 = lane & 15, lq = lane >> 4;
  int koff = lq * 8;
  size_t bL = (size_t)b * L_;
  if (t < 64) { redz[t] = 0.f; reds1[t] = 0.f; redzd[t] = 0.f; }
  int mo = (wv & 1) * 16;
  int no = (wv >> 1) * 32;
  s16x8 qf[2][8];
  #pragma unroll
  for (int nt = 0; nt < 2; ++nt) {
    const unsigned short* qrow = qe_bf + (bL + i0 + no + nt*16 + l15)*D_;
    #pragma unroll
    for (int ks = 0; ks < 8; ++ks)
      qf[nt][ks] = *(const s16x8*)(qrow + ks*32 + koff);
  }
  int mo2 = (wv & 1) * 32;
  int do_ = (wv >> 1) * 128;
  f32x4 oacc[2][8];
  f32x4 zz = {0.f, 0.f, 0.f, 0.f};
  #pragma unroll
  for (int i = 0; i < 2; ++i)
    #pragma unroll
    for (int j = 0; j < 8; ++j) oacc[i][j] = zz;
  float rzs[2] = {0.f, 0.f}, rs1[2] = {0.f, 0.f}, rzd[2] = {0.f, 0.f};
  int njt = 2*t64 + 2;
  for (int jt = 0; jt < njt; ++jt) {
    int j0 = jt * 32;
    __syncthreads();
    {
      int jr = t >> 3, seg = (t & 7) * 32;
      const uint4* src = (const uint4*)(qe_bf + (bL + j0 + jr)*D_ + seg);
      #pragma unroll
      for (int m = 0; m < 4; ++m) *(uint4*)&sK[jr*KSTR + seg + m*8] = src[m];
    }
    {
      const uint4* src = (const uint4*)(qeT + ((size_t)b*D_ + t)*L_ + j0);
      #pragma unroll
      for (int m = 0; m < 4; ++m) *(uint4*)&sKT[t*TSTR + m*8] = src[m];
    }
    if (t < 32) scj[t] = (float)cs[bL + j0 + t];
    __syncthreads();
    f32x4 sacc[2]; sacc[0] = zz; sacc[1] = zz;
    #pragma unroll
    for (int ks = 0; ks < 8; ++ks) {
      s16x8 af = *(const s16x8*)&sK[(mo + l15)*KSTR + ks*32 + koff];
      sacc[0] = __builtin_amdgcn_mfma_f32_16x16x32_bf16(af, qf[0][ks], sacc[0], 0, 0, 0);
      sacc[1] = __builtin_amdgcn_mfma_f32_16x16x32_bf16(af, qf[1][ks], sacc[1], 0, 0, 0);
    }
    #pragma unroll
    for (int nt = 0; nt < 2; ++nt) {
      int ig = i0 + no + nt*16 + l15;
      union { unsigned short u[4]; unsigned long long q; } pk;
      #pragma unroll
      for (int r = 0; r < 4; ++r) {
        int jloc = mo + lq*4 + r;
        int jg = j0 + jloc;
        float ex = __expf(sacc[nt][r]);
        float e = (jg < ig) ? ex : 0.f;
        rzs[nt] += e;
        rs1[nt] = fmaf(e, scj[jloc], rs1[nt]);
        if (jg == ig) rzd[nt] += ex;
        pk.u[r] = f2bf(e);
      }
      *(unsigned long long*)&sP[(no + nt*16 + l15)*PSTR + mo + lq*4] = pk.q;
    }
    __syncthreads();
    s16x8 paf[2];
    #pragma unroll
    for (int mt = 0; mt < 2; ++mt)
      paf[mt] = *(const s16x8*)&sP[(mo2 + mt*16 + l15)*PSTR + koff];
    #pragma unroll
    for (int nt = 0; nt < 8; ++nt) {
      s16x8 bfr = *(const s16x8*)&sKT[(do_ + nt*16 + l15)*TSTR + koff];
      oacc[0][nt] = __builtin_amdgcn_mfma_f32_16x16x32_bf16(paf[0], bfr, oacc[0][nt], 0, 0, 0);
      oacc[1][nt] = __builtin_amdgcn_mfma_f32_16x16x32_bf16(paf[1], bfr, oacc[1][nt], 0, 0, 0);
    }
  }
  #pragma unroll
  for (int nt = 0; nt < 2; ++nt) {
    float z = rzs[nt], s1 = rs1[nt], zd = rzd[nt];
    z  += __shfl_xor(z, 16);  z  += __shfl_xor(z, 32);
    s1 += __shfl_xor(s1, 16); s1 += __shfl_xor(s1, 32);
    zd += __shfl_xor(zd, 16); zd += __shfl_xor(zd, 32);
    if (lq == 0) {
      atomicAdd(&redz[no + nt*16 + l15], z);
      atomicAdd(&reds1[no + nt*16 + l15], s1);
      atomicAdd(&redzd[no + nt*16 + l15], zd);
    }
  }
  __syncthreads();
  if (t < 64) {
    float z = redz[t], zd = redzd[t], s1 = reds1[t];
    float inv = 1.0f / (z + 1e-8f*(z + zd));
    stv[bL + i0 + t] = z * inv;
    s1v[bL + i0 + t] = s1 * inv;
    redz[t] = inv;
  }
  __syncthreads();
  #pragma unroll
  for (int mt = 0; mt < 2; ++mt)
    #pragma unroll
    for (int r = 0; r < 4; ++r) {
      int iloc = mo2 + mt*16 + lq*4 + r;
      float inv = redz[iloc];
      size_t base = (bL + i0 + iloc)*D_ + do_;
      #pragma unroll
      for (int nt = 0; nt < 8; ++nt)
        attq[base + nt*16 + l15] = f2bf(oacc[mt][nt][r] * inv);
    }
}

// ---------------- weight conversion: fp32 -> bf16 --------------------------
__global__ void k_cvt(const float* __restrict__ src, unsigned short* __restrict__ dst) {
  int i = blockIdx.x*256 + threadIdx.x;
  float4 v = ((const float4*)src)[i];
  union { unsigned short u[4]; uint2 q; } o;
  o.u[0] = f2bf(v.x); o.u[1] = f2bf(v.y); o.u[2] = f2bf(v.z); o.u[3] = f2bf(v.w);
  ((uint2*)dst)[i] = o.q;
}

// ------- conv weight transpose+convert: w[l][tap][ic][oc] -> wT[l][oc][tap*256+ic]
__global__ __launch_bounds__(256) void k_cvt_convw(const float* __restrict__ w,
                                                   unsigned short* __restrict__ wT) {
  __shared__ unsigned short lds[64*72];
  int l = blockIdx.z;
  int k0 = blockIdx.x * 64;
  int oc0 = blockIdx.y * 64;
  const float* src = w + (size_t)l*524288;
  unsigned short* dst = wT + (size_t)l*524288;
  int t = threadIdx.x;
  #pragma unroll
  for (int it = 0; it < 4; ++it) {
    int kr = it*16 + (t >> 4);
    int oc = (t & 15)*4;
    float4 v = *(const float4*)(src + (size_t)(k0+kr)*512 + oc0 + oc);
    lds[(oc+0)*72 + kr] = f2bf(v.x);
    lds[(oc+1)*72 + kr] = f2bf(v.y);
    lds[(oc+2)*72 + kr] = f2bf(v.z);
    lds[(oc+3)*72 + kr] = f2bf(v.w);
  }
  __syncthreads();
  #pragma unroll
  for (int it = 0; it < 2; ++it) {
    int ocr = it*32 + (t >> 3);
    int kx = (t & 7)*8;
    *(uint4*)(dst + (size_t)(oc0+ocr)*1024 + k0 + kx) = *(const uint4*)&lds[ocr*72 + kx];
  }
}

// ---------------- K3: LDS-free register-fragment MLP GEMM ------------------
// No LDS, no barriers: A/B fragments are contiguous 8-elem k-spans in global
// memory, loaded straight to VGPRs. Wave = 64x64 quadrant of a 128x128 tile.
__global__ __launch_bounds__(256) void k_mlp_frag(
    const unsigned short* __restrict__ qe_bf, const unsigned short* __restrict__ attq,
    const float* __restrict__ stv, const float* __restrict__ s1v,
    const int* __restrict__ cs, const float* __restrict__ cqc,
    const float* __restrict__ Ec,
    const unsigned short* __restrict__ W1bf, const float* __restrict__ W1b,
    const unsigned short* __restrict__ W2bf, const float* __restrict__ W2b,
    unsigned short* __restrict__ out) {
  int t = threadIdx.x;
  int lane = t & 63, wv = t >> 6;
  int m0 = blockIdx.x * 128;
  int n0 = blockIdx.y * 128;
  int moff = (wv & 1) * 64, noff = (wv >> 1) * 64;
  int l15 = lane & 15, koff = (lane >> 4) * 8;
  int mrow[4];
  #pragma unroll
  for (int i = 0; i < 4; ++i) mrow[i] = m0 + moff + i*16 + l15;
  // loop-invariant per-row scalars
  int ci[4]; float s1r[4], s0r[4];
  #pragma unroll
  for (int i = 0; i < 4; ++i) {
    ci[i] = cs[mrow[i]];
    float s1_ = s1v[mrow[i]];
    s1r[i] = s1_; s0r[i] = stv[mrow[i]] - s1_;
  }
  const unsigned short* bp1[4]; const unsigned short* bp2[4];
  #pragma unroll
  for (int j = 0; j < 4; ++j) {
    size_t nrow = (size_t)(n0 + noff + j*16 + l15);
    bp1[j] = W1bf + nrow*1280 + koff;
    bp2[j] = W2bf + nrow*1280 + koff;
  }
  f32x4 acc1[4][4], acc2[4][4];
  f32x4 zz = {0.f, 0.f, 0.f, 0.f};
  #pragma unroll
  for (int i = 0; i < 4; ++i)
    #pragma unroll
    for (int j = 0; j < 4; ++j) { acc1[i][j] = zz; acc2[i][j] = zz; }
  for (int k0 = 0; k0 < 1280; k0 += 32) {
    int seg = k0 >> 8;
    int ks = (k0 & 255) + koff;
    s16x8 am[4];
    if (seg == 0) {
      #pragma unroll
      for (int i = 0; i < 4; ++i)
        am[i] = *(const s16x8*)(qe_bf + (size_t)mrow[i]*D_ + ks);
    } else if (seg == 2) {
      #pragma unroll
      for (int i = 0; i < 4; ++i)
        am[i] = *(const s16x8*)(attq + (size_t)mrow[i]*D_ + ks);
    } else if (seg == 1) {
      #pragma unroll
      for (int i = 0; i < 4; ++i) {
        const float4* p = (const float4*)(Ec + (size_t)ci[i]*D_ + ks);
        float f[8];
        float4 v0 = p[0], v1 = p[1];
        f[0]=v0.x; f[1]=v0.y; f[2]=v0.z; f[3]=v0.w;
        f[4]=v1.x; f[5]=v1.y; f[6]=v1.z; f[7]=v1.w;
        am[i] = pack8v(f);
      }
    } else if (seg == 3) {
      const float4* p1 = (const float4*)(Ec + D_ + ks);
      const float4* p0 = (const float4*)(Ec + ks);
      float4 e10 = p1[0], e11 = p1[1], e00 = p0[0], e01 = p0[1];
      #pragma unroll
      for (int i = 0; i < 4; ++i) {
        float f[8];
        f[0] = s1r[i]*e10.x + s0r[i]*e00.x;
        f[1] = s1r[i]*e10.y + s0r[i]*e00.y;
        f[2] = s1r[i]*e10.z + s0r[i]*e00.z;
        f[3] = s1r[i]*e10.w + s0r[i]*e00.w;
        f[4] = s1r[i]*e11.x + s0r[i]*e01.x;
        f[5] = s1r[i]*e11.y + s0r[i]*e01.y;
        f[6] = s1r[i]*e11.z + s0r[i]*e01.z;
        f[7] = s1r[i]*e11.w + s0r[i]*e01.w;
        am[i] = pack8v(f);
      }
    } else {
      #pragma unroll
      for (int i = 0; i < 4; ++i) {
        const float4* p = (const float4*)(cqc + (size_t)mrow[i]*D_ + ks);
        float f[8];
        float4 v0 = p[0], v1 = p[1];
        f[0]=v0.x; f[1]=v0.y; f[2]=v0.z; f[3]=v0.w;
        f[4]=v1.x; f[5]=v1.y; f[6]=v1.z; f[7]=v1.w;
        am[i] = pack8v(f);
      }
    }
    s16x8 b1f[4], b2f[4];
    #pragma unroll
    for (int j = 0; j < 4; ++j) {
      b1f[j] = *(const s16x8*)(bp1[j] + k0);
      b2f[j] = *(const s16x8*)(bp2[j] + k0);
    }
    #pragma unroll
    for (int i = 0; i < 4; ++i)
      #pragma unroll
      for (int j = 0; j < 4; ++j) {
        acc1[i][j] = __builtin_amdgcn_mfma_f32_16x16x32_bf16(am[i], b1f[j], acc1[i][j], 0, 0, 0);
        acc2[i][j] = __builtin_amdgcn_mfma_f32_16x16x32_bf16(am[i], b2f[j], acc2[i][j], 0, 0, 0);
      }
  }
  #pragma unroll
  for (int j = 0; j < 4; ++j) {
    int col = n0 + noff + j*16 + l15;
    float b1 = W1b[col], b2 = W2b[col];
    #pragma unroll
    for (int i = 0; i < 4; ++i) {
      int rbase = m0 + moff + i*16 + (lane >> 4)*4;
      #pragma unroll
      for (int r = 0; r < 4; ++r) {
        float z1 = acc1[i][j][r] + b1;
        float z2 = acc2[i][j][r] + b2;
        out[(size_t)(rbase + r)*D_ + col] = f2bf(z1 * sigmoidf_(z2));
      }
    }
  }
}

// ---------------- K4: LDS-free register-fragment causal conv ---------------
__global__ __launch_bounds__(256) void k_conv_frag(
    const unsigned short* __restrict__ xin, const unsigned short* __restrict__ wT,
    const float* __restrict__ bias, unsigned short* __restrict__ xout) {
  int t = threadIdx.x;
  int lane = t & 63, wv = t >> 6;
  int m0 = blockIdx.x * 128;
  int n0 = blockIdx.y * 128;
  int moff = (wv & 1) * 64, noff = (wv >> 1) * 64;
  int l15 = lane & 15, koff = (lane >> 4) * 8;
  int mrow[4], al[4];
  #pragma unroll
  for (int i = 0; i < 4; ++i) {
    mrow[i] = m0 + moff + i*16 + l15;
    al[i] = mrow[i] & (L_ - 1);
  }
  const unsigned short* bpa[4]; const unsigned short* bpb[4];
  #pragma unroll
  for (int j = 0; j < 4; ++j) {
    size_t nrow = (size_t)(n0 + noff + j*16 + l15);
    bpa[j] = wT + nrow*1024 + koff;
    bpb[j] = wT + (nrow + 256)*1024 + koff;
  }
  f32x4 acca[4][4], accb[4][4];
  f32x4 zz = {0.f, 0.f, 0.f, 0.f};
  s16x8 z8 = {0,0,0,0,0,0,0,0};
  #pragma unroll
  for (int i = 0; i < 4; ++i)
    #pragma unroll
    for (int j = 0; j < 4; ++j) { acca[i][j] = zz; accb[i][j] = zz; }
  for (int k0 = 0; k0 < 1024; k0 += 32) {
    int tap = k0 >> 8;
    int ic = (k0 & 255) + koff;
    s16x8 am[4];
    #pragma unroll
    for (int i = 0; i < 4; ++i)
      am[i] = (al[i] + tap >= 3)
            ? *(const s16x8*)(xin + (size_t)(mrow[i] + tap - 3)*D_ + ic)
            : z8;
    s16x8 baf[4], bbf[4];
    #pragma unroll
    for (int j = 0; j < 4; ++j) {
      baf[j] = *(const s16x8*)(bpa[j] + k0);
      bbf[j] = *(const s16x8*)(bpb[j] + k0);
    }
    #pragma unroll
    for (int i = 0; i < 4; ++i)
      #pragma unroll
      for (int j = 0; j < 4; ++j) {
        acca[i][j] = __builtin_amdgcn_mfma_f32_16x16x32_bf16(am[i], baf[j], acca[i][j], 0, 0, 0);
        accb[i][j] = __builtin_amdgcn_mfma_f32_16x16x32_bf16(am[i], bbf[j], accb[i][j], 0, 0, 0);
      }
  }
  #pragma unroll
  for (int j = 0; j < 4; ++j) {
    int col = n0 + noff + j*16 + l15;
    float ba = bias[col], bb = bias[col + 256];
    #pragma unroll
    for (int i = 0; i < 4; ++i) {
      int rbase = m0 + moff + i*16 + (lane >> 4)*4;
      #pragma unroll
      for (int r = 0; r < 4; ++r) {
        size_t off = (size_t)(rbase + r)*D_ + col;
        float za = acca[i][j][r] + ba;
        float zb = accb[i][j][r] + bb;
        float res = bf2f(xin[off]);
        xout[off] = f2bf(za * sigmoidf_(zb) + res);
      }
    }
  }
}

// ---------------- K5: predict = sigmoid(sum_d x*Eq[qs_next]) ---------------
__global__ void k_pred(const unsigned short* __restrict__ x, const int* __restrict__ qs,
                       const float* __restrict__ Eq, float* __restrict__ out) {
  int lane = threadIdx.x & 63;
  int wv = threadIdx.x >> 6;
  int oi = blockIdx.x*4 + wv;
  int b = oi / 1023;
  int tp = oi - b*1023;
  int row = b*L_ + tp;
  int q = qs[row + 1];
  ushort4 u = ((const ushort4*)(x + (size_t)row*D_))[lane];
  float4 qv = ((const float4*)(Eq + (size_t)q*D_))[lane];
  float s = bf2f(u.x)*qv.x + bf2f(u.y)*qv.y + bf2f(u.z)*qv.z + bf2f(u.w)*qv.w;
  #pragma unroll
  for (int off = 32; off; off >>= 1) s += __shfl_xor(s, off);
  if (lane == 0) out[oi] = sigmoidf_(s);
}

extern "C" void kernel_launch(void* const* d_in, const int* in_sizes, int n_in,
                              void* d_out, int out_size, void* d_ws, size_t ws_size,
                              hipStream_t stream) {
  const int*   qs  = (const int*)d_in[0];
  const int*   cs  = (const int*)d_in[1];
  const float* cqc = (const float*)d_in[2];
  const float* Eq  = (const float*)d_in[3];
  const float* Ec  = (const float*)d_in[4];
  const float* W1w = (const float*)d_in[5];
  const float* W1b = (const float*)d_in[6];
  const float* W2w = (const float*)d_in[7];
  const float* W2b = (const float*)d_in[8];
  const float* cw  = (const float*)d_in[9];
  const float* cb  = (const float*)d_in[10];
  float* out = (float*)d_out;

  // Workspace (MiB offsets), ~133 MiB footprint with aliasing:
  //  [0,32)   qe_bf   (dead after mlp)  -> xC
  //  [32,64)  qeT     (dead after attn) -> xB
  //  [64,96)  attq    (dead after mlp)  -> xD
  //  [96,128) xA (mlp out / conv1 in)
  //  [128,..) stv, s1v, W1bf, W2bf, wT
  char* w8 = (char*)d_ws;
  unsigned short* qe_bf = (unsigned short*)w8;
  unsigned short* qeT   = (unsigned short*)(w8 + ((size_t)32 << 20));
  unsigned short* attq  = (unsigned short*)(w8 + ((size_t)64 << 20));
  unsigned short* xA    = (unsigned short*)(w8 + ((size_t)96 << 20));
  float* stv = (float*)(w8 + ((size_t)128 << 20));
  float* s1v = stv + M_;
  unsigned short* W1bf = (unsigned short*)(s1v + M_);
  unsigned short* W2bf = W1bf + 256*1280;
  unsigned short* wT   = W2bf + 256*1280;
  unsigned short* xB = qeT;
  unsigned short* xC = qe_bf;
  unsigned short* xD = attq;

  k_cvt<<<(256*1280)/4/256, 256, 0, stream>>>(W1w, W1bf);
  k_cvt<<<(256*1280)/4/256, 256, 0, stream>>>(W2w, W2bf);
  k_cvt_convw<<<dim3(16, 8, 3), 256, 0, stream>>>(cw, wT);

  k_embedT<<<dim3(16, 64), 256, 0, stream>>>(qs, Eq, qe_bf, qeT);
  k_attn_mfma<<<1024, 256, 0, stream>>>(qe_bf, qeT, cs, attq, stv, s1v);
  k_mlp_frag<<<dim3(M_/128, 2), 256, 0, stream>>>(qe_bf, attq, stv, s1v, cs, cqc, Ec,
                                                  W1bf, W1b, W2bf, W2b, xA);
  k_conv_frag<<<dim3(M_/128, 2), 256, 0, stream>>>(xA, wT,           cb,        xB);
  k_conv_frag<<<dim3(M_/128, 2), 256, 0, stream>>>(xB, wT + 524288,  cb + 512,  xC);
  k_conv_frag<<<dim3(M_/128, 2), 256, 0, stream>>>(xC, wT + 1048576, cb + 1024, xD);
  k_pred<<<(B_*(L_-1))/4, 256, 0, stream>>>(xD, qs, Eq, out);
}

// Round 8
// 570.403 us; speedup vs baseline: 1.9106x; 1.9106x over previous
//
#include <hip/hip_runtime.h>
#include <hip/hip_bf16.h>

#define B_ 64
#define L_ 1024
#define D_ 256
#define M_ (B_*L_)

typedef __attribute__((ext_vector_type(8))) short s16x8;
typedef __attribute__((ext_vector_type(4))) float f32x4;

__device__ __forceinline__ float sigmoidf_(float z) { return 1.0f/(1.0f + __expf(-z)); }

__device__ __forceinline__ unsigned short f2bf(float x) {
  unsigned int u = __builtin_bit_cast(unsigned int, x);
  u += 0x7fffu + ((u >> 16) & 1u);          // RNE
  return (unsigned short)(u >> 16);
}
__device__ __forceinline__ float bf2f(unsigned short u) {
  unsigned int x = ((unsigned int)u) << 16;
  return __builtin_bit_cast(float, x);
}
__device__ __forceinline__ uint4 pack8(const float* f) {
  union { unsigned short u[8]; uint4 v; } r;
  #pragma unroll
  for (int i = 0; i < 8; ++i) r.u[i] = f2bf(f[i]);
  return r.v;
}

// ---------------- K1: gather+convert+transpose -----------------------------
__global__ __launch_bounds__(256) void k_embedT(const int* __restrict__ qs,
    const float* __restrict__ Eq, unsigned short* __restrict__ qe_bf,
    unsigned short* __restrict__ qeT) {
  __shared__ unsigned short tile[64*264];
  int jc = blockIdx.x;
  int b  = blockIdx.y;
  int t = threadIdx.x;
  int jr = t >> 2, seg = (t & 3) * 64;
  size_t bL = (size_t)b * L_;
  int q = qs[bL + jc*64 + jr];
  {
    const float4* src = (const float4*)(Eq + (size_t)q*D_ + seg);
    float f[8];
    #pragma unroll
    for (int m = 0; m < 8; ++m) {
      float4 v0 = src[2*m], v1 = src[2*m+1];
      f[0]=v0.x; f[1]=v0.y; f[2]=v0.z; f[3]=v0.w;
      f[4]=v1.x; f[5]=v1.y; f[6]=v1.z; f[7]=v1.w;
      *(uint4*)&tile[jr*264 + seg + m*8] = pack8(f);
    }
  }
  __syncthreads();
  {
    unsigned short* dst = qe_bf + (bL + jc*64 + jr)*D_ + seg;
    #pragma unroll
    for (int m = 0; m < 8; ++m)
      *(uint4*)(dst + m*8) = *(const uint4*)&tile[jr*264 + seg + m*8];
  }
  {
    int d = t;
    union { unsigned short u[64]; uint4 v[8]; } row;
    #pragma unroll
    for (int j = 0; j < 64; ++j) row.u[j] = tile[j*264 + d];
    unsigned short* dst = qeT + ((size_t)b*D_ + d)*L_ + jc*64;
    #pragma unroll
    for (int m = 0; m < 8; ++m) *(uint4*)(dst + m*8) = row.v[m];
  }
}

// ---------------- K2: MFMA fused causal attention (R5-validated) -----------
#define KSTR 264
#define TSTR 40
#define PSTR 40

__global__ __launch_bounds__(256) void k_attn_mfma(
    const unsigned short* __restrict__ qe_bf, const unsigned short* __restrict__ qeT,
    const int* __restrict__ cs, unsigned short* __restrict__ attq,
    float* __restrict__ stv, float* __restrict__ s1v) {
  __shared__ unsigned short sK[32*KSTR];
  __shared__ unsigned short sKT[256*TSTR];
  __shared__ unsigned short sP[64*PSTR];
  __shared__ float scj[32];
  __shared__ float redz[64], reds1[64], redzd[64];
  const int ord16[16] = {15,14,13,12, 8,9,10,11, 7,6,5,4, 0,1,2,3};
  int pos = blockIdx.x >> 6, b = blockIdx.x & 63;
  int t64 = ord16[pos];
  int i0 = t64 * 64;
  int t = threadIdx.x;
  int lane = t & 63, wv = t >> 6;
  int l15 = lane & 15, lq = lane >> 4;
  int koff = lq * 8;
  size_t bL = (size_t)b * L_;
  if (t < 64) { redz[t] = 0.f; reds1[t] = 0.f; redzd[t] = 0.f; }
  int mo = (wv & 1) * 16;
  int no = (wv >> 1) * 32;
  s16x8 qf[2][8];
  #pragma unroll
  for (int nt = 0; nt < 2; ++nt) {
    const unsigned short* qrow = qe_bf + (bL + i0 + no + nt*16 + l15)*D_;
    #pragma unroll
    for (int ks = 0; ks < 8; ++ks)
      qf[nt][ks] = *(const s16x8*)(qrow + ks*32 + koff);
  }
  int mo2 = (wv & 1) * 32;
  int do_ = (wv >> 1) * 128;
  f32x4 oacc[2][8];
  f32x4 zz = {0.f, 0.f, 0.f, 0.f};
  #pragma unroll
  for (int i = 0; i < 2; ++i)
    #pragma unroll
    for (int j = 0; j < 8; ++j) oacc[i][j] = zz;
  float rzs[2] = {0.f, 0.f}, rs1[2] = {0.f, 0.f}, rzd[2] = {0.f, 0.f};
  int njt = 2*t64 + 2;
  for (int jt = 0; jt < njt; ++jt) {
    int j0 = jt * 32;
    __syncthreads();
    {
      int jr = t >> 3, seg = (t & 7) * 32;
      const uint4* src = (const uint4*)(qe_bf + (bL + j0 + jr)*D_ + seg);
      #pragma unroll
      for (int m = 0; m < 4; ++m) *(uint4*)&sK[jr*KSTR + seg + m*8] = src[m];
    }
    {
      const uint4* src = (const uint4*)(qeT + ((size_t)b*D_ + t)*L_ + j0);
      #pragma unroll
      for (int m = 0; m < 4; ++m) *(uint4*)&sKT[t*TSTR + m*8] = src[m];
    }
    if (t < 32) scj[t] = (float)cs[bL + j0 + t];
    __syncthreads();
    f32x4 sacc[2]; sacc[0] = zz; sacc[1] = zz;
    #pragma unroll
    for (int ks = 0; ks < 8; ++ks) {
      s16x8 af = *(const s16x8*)&sK[(mo + l15)*KSTR + ks*32 + koff];
      sacc[0] = __builtin_amdgcn_mfma_f32_16x16x32_bf16(af, qf[0][ks], sacc[0], 0, 0, 0);
      sacc[1] = __builtin_amdgcn_mfma_f32_16x16x32_bf16(af, qf[1][ks], sacc[1], 0, 0, 0);
    }
    #pragma unroll
    for (int nt = 0; nt < 2; ++nt) {
      int ig = i0 + no + nt*16 + l15;
      union { unsigned short u[4]; unsigned long long q; } pk;
      #pragma unroll
      for (int r = 0; r < 4; ++r) {
        int jloc = mo + lq*4 + r;
        int jg = j0 + jloc;
        float ex = __expf(sacc[nt][r]);
        float e = (jg < ig) ? ex : 0.f;
        rzs[nt] += e;
        rs1[nt] = fmaf(e, scj[jloc], rs1[nt]);
        if (jg == ig) rzd[nt] += ex;
        pk.u[r] = f2bf(e);
      }
      *(unsigned long long*)&sP[(no + nt*16 + l15)*PSTR + mo + lq*4] = pk.q;
    }
    __syncthreads();
    s16x8 paf[2];
    #pragma unroll
    for (int mt = 0; mt < 2; ++mt)
      paf[mt] = *(const s16x8*)&sP[(mo2 + mt*16 + l15)*PSTR + koff];
    #pragma unroll
    for (int nt = 0; nt < 8; ++nt) {
      s16x8 bfr = *(const s16x8*)&sKT[(do_ + nt*16 + l15)*TSTR + koff];
      oacc[0][nt] = __builtin_amdgcn_mfma_f32_16x16x32_bf16(paf[0], bfr, oacc[0][nt], 0, 0, 0);
      oacc[1][nt] = __builtin_amdgcn_mfma_f32_16x16x32_bf16(paf[1], bfr, oacc[1][nt], 0, 0, 0);
    }
  }
  #pragma unroll
  for (int nt = 0; nt < 2; ++nt) {
    float z = rzs[nt], s1 = rs1[nt], zd = rzd[nt];
    z  += __shfl_xor(z, 16);  z  += __shfl_xor(z, 32);
    s1 += __shfl_xor(s1, 16); s1 += __shfl_xor(s1, 32);
    zd += __shfl_xor(zd, 16); zd += __shfl_xor(zd, 32);
    if (lq == 0) {
      atomicAdd(&redz[no + nt*16 + l15], z);
      atomicAdd(&reds1[no + nt*16 + l15], s1);
      atomicAdd(&redzd[no + nt*16 + l15], zd);
    }
  }
  __syncthreads();
  if (t < 64) {
    float z = redz[t], zd = redzd[t], s1 = reds1[t];
    float inv = 1.0f / (z + 1e-8f*(z + zd));
    stv[bL + i0 + t] = z * inv;
    s1v[bL + i0 + t] = s1 * inv;
    redz[t] = inv;
  }
  __syncthreads();
  #pragma unroll
  for (int mt = 0; mt < 2; ++mt)
    #pragma unroll
    for (int r = 0; r < 4; ++r) {
      int iloc = mo2 + mt*16 + lq*4 + r;
      float inv = redz[iloc];
      size_t base = (bL + i0 + iloc)*D_ + do_;
      #pragma unroll
      for (int nt = 0; nt < 8; ++nt)
        attq[base + nt*16 + l15] = f2bf(oacc[mt][nt][r] * inv);
    }
}

// ------- MLP weight swizzle: frag order, A-side segments [qe|HRPq|cqc] -----
// frag ks 0..7 -> H col 0..255 (qe); 8..15 -> 512..767 (HRPq); 16..23 ->
// 1024..1279 (cqc). (ce / HRP-ce segments live in the T/U epilogue tables.)
__global__ void k_cvt_sw(const float* __restrict__ W, unsigned short* __restrict__ Wf) {
  int tid = blockIdx.x*256 + threadIdx.x;      // 96 blocks: 384 frags x 64 lanes
  int lane = tid & 63;
  int frag = tid >> 6;
  int ks = frag % 24;
  int nt = frag / 24;
  int n = nt*16 + (lane & 15);
  int seg = ks >> 3;                           // 0,1,2
  int kor = (seg == 0 ? 0 : (seg == 1 ? 512 : 1024)) + (ks & 7)*32 + (lane >> 4)*8;
  const float4* src = (const float4*)(W + (size_t)n*1280 + kor);
  float f[8];
  float4 a = src[0], b = src[1];
  f[0]=a.x; f[1]=a.y; f[2]=a.z; f[3]=a.w; f[4]=b.x; f[5]=b.y; f[6]=b.z; f[7]=b.w;
  *(uint4*)(Wf + (size_t)frag*512 + (size_t)lane*8) = pack8(f);
}

// ------- conv weight swizzle: w[l][tap][ic][oc] -> frag order (linear k) ----
__global__ void k_cvt_convw_sw(const float* __restrict__ w,
                               unsigned short* __restrict__ wTf) {
  int tid = blockIdx.x*256 + threadIdx.x;      // 256 blocks/layer: 1024 frags
  int l = blockIdx.y;
  int lane = tid & 63;
  int frag = tid >> 6;
  int ks = frag & 31, nt = frag >> 5;
  int oc = nt*16 + (lane & 15);
  int k = ks*32 + (lane >> 4)*8;
  int tap = k >> 8, ic = k & 255;
  const float* src = w + (size_t)l*524288 + ((size_t)(tap*256 + ic))*512 + oc;
  float f[8];
  #pragma unroll
  for (int e = 0; e < 8; ++e) f[e] = src[(size_t)e*512];
  *(uint4*)(wTf + (size_t)l*524288 + (size_t)frag*512 + (size_t)lane*8) = pack8(f);
}

// ------- T/U tables: collapse ce & HRP-ce segments of H@W to per-col consts -
// tu[0..255]=T0 tu[256..]=T1 tu[512..]=U0 tu[768..]=U1 for W1; +1024 for W2.
__global__ __launch_bounds__(256) void k_tu(const float* __restrict__ Ec,
    const float* __restrict__ W1w, const float* __restrict__ W2w,
    float* __restrict__ tu) {
  int n = blockIdx.x;
  int wv = threadIdx.x >> 6, lane = threadIdx.x & 63;
  int v = wv & 1;
  int reg = (wv >> 1) ? 768 : 256;
  const float* e  = Ec + (size_t)v*D_ + lane*4;
  const float* w1 = W1w + (size_t)n*1280 + reg + lane*4;
  const float* w2 = W2w + (size_t)n*1280 + reg + lane*4;
  float d1 = 0.f, d2 = 0.f;
  #pragma unroll
  for (int m = 0; m < 4; ++m) {
    float ev = e[m];
    d1 = fmaf(ev, w1[m], d1);
    d2 = fmaf(ev, w2[m], d2);
  }
  #pragma unroll
  for (int off = 32; off; off >>= 1) { d1 += __shfl_xor(d1, off); d2 += __shfl_xor(d2, off); }
  if (lane == 0) { tu[wv*256 + n] = d1; tu[1024 + wv*256 + n] = d2; }
}

// ---------------- K3: hybrid MFMA MLP (K=768) ------------------------------
// A: LDS frag-order double-buffer, 1 barrier/step. B: coalesced frag loads
// from pre-swizzled global (L2-resident). Wave = 128 rows x 32 cols.
__global__ __launch_bounds__(256, 2) void k_mlp_hyb(
    const unsigned short* __restrict__ qe_bf, const unsigned short* __restrict__ attq,
    const float* __restrict__ stv, const float* __restrict__ s1v,
    const int* __restrict__ cs, const float* __restrict__ cqc,
    const unsigned short* __restrict__ W1f, const float* __restrict__ W1b,
    const unsigned short* __restrict__ W2f, const float* __restrict__ W2b,
    const float* __restrict__ tu, unsigned short* __restrict__ out) {
  __shared__ unsigned short sA[2][4096];      // [buf][mt*64+lane][8] = 8KB each
  int t = threadIdx.x;
  int lane = t & 63, wv = t >> 6;
  int m0 = blockIdx.x * 128;
  int n0 = blockIdx.y * 128;
  int l15 = lane & 15, lq = lane >> 4;
  int lr = t >> 1, kh = (t & 1) * 16;
  int arow = m0 + lr;
  int sbase = ((lr >> 4)*64 + (kh >> 3)*16 + (lr & 15))*8;
  int ntb = (n0 >> 4) + wv*2;
  f32x4 acc1[8][2], acc2[8][2];
  f32x4 zz = {0.f, 0.f, 0.f, 0.f};
  #pragma unroll
  for (int i = 0; i < 8; ++i) { acc1[i][0]=zz; acc1[i][1]=zz; acc2[i][0]=zz; acc2[i][1]=zz; }

  auto stage_load = [&](int s, uint4* sr) {
    int ks = (s & 7)*32 + kh;
    if (s < 8) {
      const uint4* p = (const uint4*)(qe_bf + (size_t)arow*D_ + ks);
      sr[0] = p[0]; sr[1] = p[1];
    } else if (s < 16) {
      const uint4* p = (const uint4*)(attq + (size_t)arow*D_ + ks);
      sr[0] = p[0]; sr[1] = p[1];
    } else {
      const uint4* p = (const uint4*)(cqc + (size_t)arow*D_ + ks);  // 16 fp32
      sr[0] = p[0]; sr[1] = p[1]; sr[2] = p[2]; sr[3] = p[3];
    }
  };
  auto stage_write = [&](int s, const uint4* sr, int b) {
    unsigned short* dst = &sA[b][sbase];
    if (s < 16) {
      *(uint4*)dst = sr[0];
      *(uint4*)(dst + 128) = sr[1];
    } else {
      const float* f = (const float*)sr;
      *(uint4*)dst = pack8(f);
      *(uint4*)(dst + 128) = pack8(f + 8);
    }
  };
  auto loadB = [&](int s, s16x8* B1, s16x8* B2) {
    #pragma unroll
    for (int j = 0; j < 2; ++j) {
      size_t off = ((size_t)(ntb + j)*24 + s)*512 + (size_t)lane*8;
      B1[j] = *(const s16x8*)(W1f + off);
      B2[j] = *(const s16x8*)(W2f + off);
    }
  };

  uint4 sr[4];
  s16x8 bc1[2], bc2[2];
  stage_load(0, sr);
  stage_write(0, sr, 0);
  loadB(0, bc1, bc2);
  __syncthreads();
  for (int s = 0; s < 24; ++s) {
    int nxt = s + 1;
    uint4 srn[4];
    s16x8 bn1[2], bn2[2];
    if (nxt < 24) {
      loadB(nxt, bn1, bn2);
      stage_load(nxt, srn);
    }
    int cur = s & 1;
    s16x8 am[8];
    #pragma unroll
    for (int mt = 0; mt < 8; ++mt)
      am[mt] = *(const s16x8*)&sA[cur][(mt*64 + lane)*8];
    #pragma unroll
    for (int mt = 0; mt < 8; ++mt) {
      acc1[mt][0] = __builtin_amdgcn_mfma_f32_16x16x32_bf16(am[mt], bc1[0], acc1[mt][0], 0, 0, 0);
      acc1[mt][1] = __builtin_amdgcn_mfma_f32_16x16x32_bf16(am[mt], bc1[1], acc1[mt][1], 0, 0, 0);
      acc2[mt][0] = __builtin_amdgcn_mfma_f32_16x16x32_bf16(am[mt], bc2[0], acc2[mt][0], 0, 0, 0);
      acc2[mt][1] = __builtin_amdgcn_mfma_f32_16x16x32_bf16(am[mt], bc2[1], acc2[mt][1], 0, 0, 0);
    }
    if (nxt < 24) {
      stage_write(nxt, srn, cur ^ 1);
      bc1[0]=bn1[0]; bc1[1]=bn1[1]; bc2[0]=bn2[0]; bc2[1]=bn2[1];
    }
    __syncthreads();
  }
  // epilogue: + bias + (c? T1:T0) + s0*U0 + s1*U1, GLU
  int cols[2]; float cb1[2], cb2[2];
  float t1a[2], t1b[2], u1a[2], u1b[2], t2a[2], t2b[2], u2a[2], u2b[2];
  #pragma unroll
  for (int j = 0; j < 2; ++j) {
    int col = n0 + wv*32 + j*16 + l15;
    cols[j] = col;
    cb1[j] = W1b[col]; cb2[j] = W2b[col];
    t1a[j] = tu[col];       t1b[j] = tu[256+col];
    u1a[j] = tu[512+col];   u1b[j] = tu[768+col];
    t2a[j] = tu[1024+col];  t2b[j] = tu[1280+col];
    u2a[j] = tu[1536+col];  u2b[j] = tu[1792+col];
  }
  #pragma unroll
  for (int mt = 0; mt < 8; ++mt) {
    int rbase = m0 + mt*16 + lq*4;
    #pragma unroll
    for (int r = 0; r < 4; ++r) {
      int row = rbase + r;
      int c = cs[row];
      float s1r = s1v[row];
      float s0r = stv[row] - s1r;
      #pragma unroll
      for (int j = 0; j < 2; ++j) {
        float z1 = acc1[mt][j][r] + cb1[j] + (c ? t1b[j] : t1a[j]) + s0r*u1a[j] + s1r*u1b[j];
        float z2 = acc2[mt][j][r] + cb2[j] + (c ? t2b[j] : t2a[j]) + s0r*u2a[j] + s1r*u2b[j];
        out[(size_t)row*D_ + cols[j]] = f2bf(z1 * sigmoidf_(z2));
      }
    }
  }
}

// ---------------- K4: hybrid MFMA causal conv K=4 + GLU + residual ---------
__global__ __launch_bounds__(256, 2) void k_conv_hyb(
    const unsigned short* __restrict__ xin, const unsigned short* __restrict__ wTf,
    const float* __restrict__ bias, unsigned short* __restrict__ xout) {
  __shared__ unsigned short sA[2][4096];
  int t = threadIdx.x;
  int lane = t & 63, wv = t >> 6;
  int m0 = blockIdx.x * 128;
  int n0 = blockIdx.y * 128;
  int l15 = lane & 15, lq = lane >> 4;
  int lr = t >> 1, kh = (t & 1) * 16;
  int arow = m0 + lr;
  int al = arow & (L_ - 1);
  int sbase = ((lr >> 4)*64 + (kh >> 3)*16 + (lr & 15))*8;
  int nta = (n0 >> 4) + wv*2;
  f32x4 acca[8][2], accb[8][2];
  f32x4 zz = {0.f, 0.f, 0.f, 0.f};
  #pragma unroll
  for (int i = 0; i < 8; ++i) { acca[i][0]=zz; acca[i][1]=zz; accb[i][0]=zz; accb[i][1]=zz; }

  auto stage_load = [&](int s, uint4* sr) {
    int tap = s >> 3;
    uint4 z4 = {0,0,0,0};
    sr[0] = z4; sr[1] = z4;
    if (al + tap >= 3) {
      const uint4* p = (const uint4*)(xin + (size_t)(arow + tap - 3)*D_ + (s & 7)*32 + kh);
      sr[0] = p[0]; sr[1] = p[1];
    }
  };
  auto loadB = [&](int s, s16x8* Ba, s16x8* Bb) {
    #pragma unroll
    for (int j = 0; j < 2; ++j) {
      size_t off = ((size_t)(nta + j)*32 + s)*512 + (size_t)lane*8;
      Ba[j] = *(const s16x8*)(wTf + off);
      Bb[j] = *(const s16x8*)(wTf + off + 262144);   // b-half: +16 ntiles
    }
  };

  uint4 sr[2];
  s16x8 bca[2], bcb[2];
  stage_load(0, sr);
  { unsigned short* dst = &sA[0][sbase]; *(uint4*)dst = sr[0]; *(uint4*)(dst+128) = sr[1]; }
  loadB(0, bca, bcb);
  __syncthreads();
  for (int s = 0; s < 32; ++s) {
    int nxt = s + 1;
    uint4 srn[2];
    s16x8 bna[2], bnb[2];
    if (nxt < 32) {
      loadB(nxt, bna, bnb);
      stage_load(nxt, srn);
    }
    int cur = s & 1;
    s16x8 am[8];
    #pragma unroll
    for (int mt = 0; mt < 8; ++mt)
      am[mt] = *(const s16x8*)&sA[cur][(mt*64 + lane)*8];
    #pragma unroll
    for (int mt = 0; mt < 8; ++mt) {
      acca[mt][0] = __builtin_amdgcn_mfma_f32_16x16x32_bf16(am[mt], bca[0], acca[mt][0], 0, 0, 0);
      acca[mt][1] = __builtin_amdgcn_mfma_f32_16x16x32_bf16(am[mt], bca[1], acca[mt][1], 0, 0, 0);
      accb[mt][0] = __builtin_amdgcn_mfma_f32_16x16x32_bf16(am[mt], bcb[0], accb[mt][0], 0, 0, 0);
      accb[mt][1] = __builtin_amdgcn_mfma_f32_16x16x32_bf16(am[mt], bcb[1], accb[mt][1], 0, 0, 0);
    }
    if (nxt < 32) {
      unsigned short* dst = &sA[cur ^ 1][sbase];
      *(uint4*)dst = srn[0];
      *(uint4*)(dst + 128) = srn[1];
      bca[0]=bna[0]; bca[1]=bna[1]; bcb[0]=bnb[0]; bcb[1]=bnb[1];
    }
    __syncthreads();
  }
  #pragma unroll
  for (int j = 0; j < 2; ++j) {
    int col = n0 + wv*32 + j*16 + l15;
    float ba = bias[col], bb = bias[col + 256];
    #pragma unroll
    for (int mt = 0; mt < 8; ++mt) {
      int rbase = m0 + mt*16 + lq*4;
      #pragma unroll
      for (int r = 0; r < 4; ++r) {
        size_t off = (size_t)(rbase + r)*D_ + col;
        float za = acca[mt][j][r] + ba;
        float zb = accb[mt][j][r] + bb;
        float res = bf2f(xin[off]);
        xout[off] = f2bf(za * sigmoidf_(zb) + res);
      }
    }
  }
}

// ---------------- K5: predict = sigmoid(sum_d x*Eq[qs_next]) ---------------
__global__ void k_pred(const unsigned short* __restrict__ x, const int* __restrict__ qs,
                       const float* __restrict__ Eq, float* __restrict__ out) {
  int lane = threadIdx.x & 63;
  int wv = threadIdx.x >> 6;
  int oi = blockIdx.x*4 + wv;
  int b = oi / 1023;
  int tp = oi - b*1023;
  int row = b*L_ + tp;
  int q = qs[row + 1];
  ushort4 u = ((const ushort4*)(x + (size_t)row*D_))[lane];
  float4 qv = ((const float4*)(Eq + (size_t)q*D_))[lane];
  float s = bf2f(u.x)*qv.x + bf2f(u.y)*qv.y + bf2f(u.z)*qv.z + bf2f(u.w)*qv.w;
  #pragma unroll
  for (int off = 32; off; off >>= 1) s += __shfl_xor(s, off);
  if (lane == 0) out[oi] = sigmoidf_(s);
}

extern "C" void kernel_launch(void* const* d_in, const int* in_sizes, int n_in,
                              void* d_out, int out_size, void* d_ws, size_t ws_size,
                              hipStream_t stream) {
  const int*   qs  = (const int*)d_in[0];
  const int*   cs  = (const int*)d_in[1];
  const float* cqc = (const float*)d_in[2];
  const float* Eq  = (const float*)d_in[3];
  const float* Ec  = (const float*)d_in[4];
  const float* W1w = (const float*)d_in[5];
  const float* W1b = (const float*)d_in[6];
  const float* W2w = (const float*)d_in[7];
  const float* W2b = (const float*)d_in[8];
  const float* cw  = (const float*)d_in[9];
  const float* cb  = (const float*)d_in[10];
  float* out = (float*)d_out;

  // Workspace (MiB offsets), ~133 MiB with aliasing:
  //  [0,32)   qe_bf (dead after mlp)  -> xC
  //  [32,64)  qeT   (dead after attn) -> xB
  //  [64,96)  attq  (dead after mlp)  -> xD
  //  [96,128) xA (mlp out / conv1 in)
  //  [128,..) stv, s1v, W1f, W2f, wTf, tu
  char* w8 = (char*)d_ws;
  unsigned short* qe_bf = (unsigned short*)w8;
  unsigned short* qeT   = (unsigned short*)(w8 + ((size_t)32 << 20));
  unsigned short* attq  = (unsigned short*)(w8 + ((size_t)64 << 20));
  unsigned short* xA    = (unsigned short*)(w8 + ((size_t)96 << 20));
  float* stv = (float*)(w8 + ((size_t)128 << 20));
  float* s1v = stv + M_;
  unsigned short* W1f = (unsigned short*)(s1v + M_);
  unsigned short* W2f = W1f + 384*512;
  unsigned short* wTf = W2f + 384*512;           // 3 layers x 1024 frags x 512
  float* tu = (float*)(wTf + (size_t)3*524288);  // 2048 floats
  unsigned short* xB = qeT;
  unsigned short* xC = qe_bf;
  unsigned short* xD = attq;

  k_cvt_sw<<<96, 256, 0, stream>>>(W1w, W1f);
  k_cvt_sw<<<96, 256, 0, stream>>>(W2w, W2f);
  k_cvt_convw_sw<<<dim3(256, 3), 256, 0, stream>>>(cw, wTf);
  k_tu<<<256, 256, 0, stream>>>(Ec, W1w, W2w, tu);

  k_embedT<<<dim3(16, 64), 256, 0, stream>>>(qs, Eq, qe_bf, qeT);
  k_attn_mfma<<<1024, 256, 0, stream>>>(qe_bf, qeT, cs, attq, stv, s1v);
  k_mlp_hyb<<<dim3(M_/128, 2), 256, 0, stream>>>(qe_bf, attq, stv, s1v, cs, cqc,
                                                 W1f, W1b, W2f, W2b, tu, xA);
  k_conv_hyb<<<dim3(M_/128, 2), 256, 0, stream>>>(xA, wTf,           cb,        xB);
  k_conv_hyb<<<dim3(M_/128, 2), 256, 0, stream>>>(xB, wTf + 524288,  cb + 512,  xC);
  k_conv_hyb<<<dim3(M_/128, 2), 256, 0, stream>>>(xC, wTf + 1048576, cb + 1024, xD);
  k_pred<<<(B_*(L_-1))/4, 256, 0, stream>>>(xD, qs, Eq, out);
}